// Round 12
// baseline (167.909 us; speedup 1.0000x reference)
//
#include <hip/hip_runtime.h>

typedef __bf16 bf16;
typedef __bf16 bf16x4 __attribute__((ext_vector_type(4)));
typedef __bf16 bf16x8 __attribute__((ext_vector_type(8)));
typedef float f32x4 __attribute__((ext_vector_type(4)));
typedef float f32x16 __attribute__((ext_vector_type(16)));
typedef unsigned u32x4 __attribute__((ext_vector_type(4)));

static constexpr int Bn = 2, Sn = 2048, Dn = 1024, Hn = 16, HDn = 64;

__device__ __forceinline__ void gload_lds16(const void* g, void* l) {
  __builtin_amdgcn_global_load_lds((__attribute__((address_space(1))) void*)g,
                                   (__attribute__((address_space(3))) void*)l, 16, 0, 0);
}

__device__ __forceinline__ f32x4 mfma_bf16_16x16x32(bf16x8 a, bf16x8 b, f32x4 c) {
  return __builtin_amdgcn_mfma_f32_16x16x32_bf16(a, b, c, 0, 0, 0);
}

__device__ __forceinline__ f32x16 mfma_bf16_32x32x16(bf16x8 a, bf16x8 b, f32x16 c) {
  return __builtin_amdgcn_mfma_f32_32x32x16_bf16(a, b, c, 0, 0, 0);
}

__device__ __forceinline__ float fast_exp2(float x) {
  float r;
  asm("v_exp_f32 %0, %1" : "=v"(r) : "v"(x));
  return r;
}

__device__ __forceinline__ unsigned cvt_pk_bf16(float lo, float hi) {
  unsigned r;
  asm("v_cvt_pk_bf16_f32 %0, %1, %2" : "=v"(r) : "v"(lo), "v"(hi));
  return r;
}

// Cross-half (lane ^ 32) combine via known-good shfl_xor (ds_bpermute path).
__device__ __forceinline__ float cross_half_max(float v) {
  return fmaxf(v, __shfl_xor(v, 32, 64));
}
__device__ __forceinline__ float cross_half_add(float v) {
  return v + __shfl_xor(v, 32, 64);
}
__device__ __forceinline__ unsigned shfl32u(unsigned u) {
  return (unsigned)__shfl_xor((int)u, 32, 64);
}

// ---------------- fp32 -> bf16 converts (fused launches) ----------------
__global__ __launch_bounds__(256) void cvt_qkv(const float* __restrict__ a0,
                                               const float* __restrict__ a1,
                                               const float* __restrict__ a2,
                                               bf16* __restrict__ o0,
                                               bf16* __restrict__ o1,
                                               bf16* __restrict__ o2, int n4) {
  const float* in = blockIdx.z == 0 ? a0 : (blockIdx.z == 1 ? a1 : a2);
  bf16* out = blockIdx.z == 0 ? o0 : (blockIdx.z == 1 ? o1 : o2);
  int i = blockIdx.x * 256 + threadIdx.x;
  const int stride = gridDim.x * 256;
  for (; i < n4; i += stride) {
    float4 v = reinterpret_cast<const float4*>(in)[i];
    bf16x4 o;
    o[0] = (bf16)v.x; o[1] = (bf16)v.y; o[2] = (bf16)v.z; o[3] = (bf16)v.w;
    reinterpret_cast<bf16x4*>(out)[i] = o;
  }
}

__global__ __launch_bounds__(256) void cvt_w(const float* __restrict__ a0,
                                             const float* __restrict__ a1,
                                             const float* __restrict__ a2,
                                             const float* __restrict__ a3,
                                             bf16* __restrict__ o0,
                                             bf16* __restrict__ o1,
                                             bf16* __restrict__ o2,
                                             bf16* __restrict__ o3,
                                             int n4, float s0) {
  const float* in; bf16* out; float s = 1.0f;
  switch (blockIdx.z) {
    case 0: in = a0; out = o0; s = s0; break;  // Wq gets softmax scale * log2(e)
    case 1: in = a1; out = o1; break;
    case 2: in = a2; out = o2; break;
    default: in = a3; out = o3; break;
  }
  int i = blockIdx.x * 256 + threadIdx.x;
  const int stride = gridDim.x * 256;
  for (; i < n4; i += stride) {
    float4 v = reinterpret_cast<const float4*>(in)[i];
    bf16x4 o;
    o[0] = (bf16)(v.x * s); o[1] = (bf16)(v.y * s);
    o[2] = (bf16)(v.z * s); o[3] = (bf16)(v.w * s);
    reinterpret_cast<bf16x4*>(out)[i] = o;
  }
}

// ---------------- GEMM: C[M,N] = A[M,K] * B[N,K]^T  (m97 structure, bf16 A) -------------
__device__ __forceinline__ void store_out(float* C, size_t i, float v) { C[i] = v; }
__device__ __forceinline__ void store_out(bf16* C, size_t i, float v) { C[i] = (bf16)v; }

template <typename OutT>
__device__ __forceinline__ void gemm_bt_dev(const bf16* __restrict__ A,
                                            const bf16* __restrict__ Bw,
                                            OutT* __restrict__ C,
                                            int K, int N) {
  const int t = threadIdx.x;
  const int l = t & 63, w = t >> 6;
  const int wr = w >> 1, wc = w & 1;
  const int lc = l & 15, lg = l >> 4;
  const int row0 = blockIdx.y * 128;
  const int col0 = blockIdx.x * 128;

  __shared__ bf16 As[128 * 32];
  __shared__ bf16 Bs[128 * 32];

  f32x4 acc[4][4] = {};

  for (int k0 = 0; k0 < K; k0 += 32) {
#pragma unroll
    for (int i = 0; i < 2; ++i) {
      const int c = i * 256 + t;
      const int r = c >> 2;
      const int scc = (c & 3) ^ (r & 3);
      gload_lds16(A + (size_t)(row0 + r) * K + k0 + scc * 8, As + c * 8);
      gload_lds16(Bw + (size_t)(col0 + r) * K + k0 + scc * 8, Bs + c * 8);
    }
    __syncthreads();

    bf16x8 af[4], bfr[4];
#pragma unroll
    for (int m = 0; m < 4; ++m) {
      const int r = wr * 64 + m * 16 + lc;
      af[m] = *reinterpret_cast<const bf16x8*>(As + r * 32 + ((lg ^ (r & 3)) * 8));
    }
#pragma unroll
    for (int n = 0; n < 4; ++n) {
      const int r = wc * 64 + n * 16 + lc;
      bfr[n] = *reinterpret_cast<const bf16x8*>(Bs + r * 32 + ((lg ^ (r & 3)) * 8));
    }
#pragma unroll
    for (int m = 0; m < 4; ++m)
#pragma unroll
      for (int n = 0; n < 4; ++n)
        acc[m][n] = mfma_bf16_16x16x32(af[m], bfr[n], acc[m][n]);
    __syncthreads();
  }

#pragma unroll
  for (int m = 0; m < 4; ++m) {
    const int rbase = row0 + wr * 64 + m * 16 + lg * 4;
#pragma unroll
    for (int n = 0; n < 4; ++n) {
      const int col = col0 + wc * 64 + n * 16 + lc;
#pragma unroll
      for (int j = 0; j < 4; ++j)
        store_out(C, (size_t)(rbase + j) * N + col, acc[m][n][j]);
    }
  }
}

__global__ __launch_bounds__(256) void gemm_qkv(
    const bf16* __restrict__ qa, const bf16* __restrict__ wq, bf16* __restrict__ qo,
    const bf16* __restrict__ ka, const bf16* __restrict__ wk, bf16* __restrict__ ko,
    const bf16* __restrict__ va, const bf16* __restrict__ wv, bf16* __restrict__ vo) {
  const bf16 *A, *Bw;
  bf16* C;
  if (blockIdx.z == 0)      { A = qa; Bw = wq; C = qo; }
  else if (blockIdx.z == 1) { A = ka; Bw = wk; C = ko; }
  else                      { A = va; Bw = wv; C = vo; }
  gemm_bt_dev<bf16>(A, Bw, C, Dn, Dn);
}

__global__ __launch_bounds__(256) void gemm_out_f32(const bf16* __restrict__ A,
                                                    const bf16* __restrict__ Bw,
                                                    float* __restrict__ C) {
  gemm_bt_dev<float>(A, Bw, C, Dn, Dn);
}

// ---------------- per-batch transpose (S x D) -> (D x S) for V ----------------
__global__ __launch_bounds__(256) void transpose_bsd(const bf16* __restrict__ in,
                                                     bf16* __restrict__ out) {
  __shared__ bf16 tile[64][66];
  const int s0 = blockIdx.x * 64, d0 = blockIdx.y * 64, b = blockIdx.z;
  const int t = threadIdx.x;
#pragma unroll
  for (int i = 0; i < 2; ++i) {
    const int c = i * 256 + t;
    const int r = c >> 3, cc = (c & 7) * 8;
    const bf16x8 v = *reinterpret_cast<const bf16x8*>(
        in + ((size_t)b * Sn + s0 + r) * Dn + d0 + cc);
#pragma unroll
    for (int j = 0; j < 8; ++j) tile[r][cc + j] = v[j];
  }
  __syncthreads();
#pragma unroll
  for (int i = 0; i < 2; ++i) {
    const int c = i * 256 + t;
    const int r = c >> 3, cc = (c & 7) * 8;
    bf16x8 v;
#pragma unroll
    for (int j = 0; j < 8; ++j) v[j] = tile[cc + j][r];
    *reinterpret_cast<bf16x8*>(out + ((size_t)b * Dn + d0 + r) * Sn + s0 + cc) = v;
  }
}

// ---------------- causal flash attention (v10: zero-staging, L2-direct gathers) ----------
// qp pre-scaled by (1/8)*log2(e) via Wq; softmax in exp2 domain.
// qp,kp: (B,S,D); vt: (B,D,S); ctx: (B,S,D)
// R11 showed FETCH=12MB: all K/V re-reads are L2-hits (XCD-pinned 2MB working set).
// So the LDS staging machinery (barriers, vmcnt, 80KB residency) was the cost, not the
// data movement (Common-mistake #7). v10 deletes it: K and V MFMA fragments are loaded
// per-lane DIRECTLY from global (16B contiguous; rows stride 2KB; L2-hit ~200-400cy),
// issued one phase early so softmax/PV latency covers them. No loop LDS, no loop
// barriers. Block = 2 waves (128 thr) = one 32-row Q tile; wave0/wave1 split the KV
// range (chunk0/chunk1), merge (m,l,O) via an 8.7KB LDS buffer + one __syncthreads.
// Grid 2048 = 64 qt x 32 (h,b), XCD-pinned (4 groups/XCD), heavy-first; VGPR ~170 ->
// ~3 waves/SIMD capacity (~1536 blocks) < 2048 -> real oversubscription + refill.
__global__ __launch_bounds__(128) void flash_attn(const bf16* __restrict__ qp,
                                                  const bf16* __restrict__ kp,
                                                  const bf16* __restrict__ vt,
                                                  bf16* __restrict__ ctx) {
  const int n = blockIdx.x;
  const int r8 = n >> 3;
  const int g = (n & 7) + 8 * (r8 >> 6);   // (h,b) group pinned to XCD n%8
  const int m = r8 & 63;
  const int qt = 63 - m;                   // heavy-first within group
  const int h = g & 15;
  const int b = g >> 4;
  const int w = threadIdx.x >> 6, l = threadIdx.x & 63;
  const int lq = l & 31, hi = l >> 5;
  const int qrow0 = qt * 32;

  const int nkv = (qt >> 1) + 1;           // KV tiles covering rows [0, qrow0+31]
  const int cnt0 = (nkv + 1) >> 1;
  const int cnt = w ? (nkv - cnt0) : cnt0; // wave0: [0,cnt0), wave1: [cnt0,nkv)
  const int tbase = w ? cnt0 : 0;

  __shared__ float OpL[32 * 65];           // wave1 O-partial, padded stride 65
  __shared__ float MlL[64];                // wave1 m[32], l[32]

  const bf16* kb = kp + ((size_t)b * Sn) * Dn + h * HDn;        // + kv*Dn + d
  const bf16* vb = vt + ((size_t)b * Dn + h * HDn) * (size_t)Sn; // + d*Sn + kv

  // Q fragments: lane holds q=lq, k-slice = kk*16 + hi*8
  bf16x8 qf[4];
#pragma unroll
  for (int kk = 0; kk < 4; ++kk)
    qf[kk] = *reinterpret_cast<const bf16x8*>(
        qp + ((size_t)b * Sn + qrow0 + lq) * Dn + h * HDn + kk * 16 + hi * 8);

  f32x16 oacc0 = {}, oacc1 = {};  // O^T partial: d 0..31 / 32..63, q = lq
  float mrow = -1e30f, lsum = 0.0f;

  // K fragments for the first tile (software-pipelined: reloaded after each QK)
  bf16x8 kf0[4], kf1[4];
  if (cnt > 0) {
    const size_t kv0 = (size_t)(tbase)*64;
#pragma unroll
    for (int kk = 0; kk < 4; ++kk) {
      kf0[kk] = *reinterpret_cast<const bf16x8*>(kb + (kv0 + lq) * Dn + kk * 16 + hi * 8);
      kf1[kk] = *reinterpret_cast<const bf16x8*>(kb + (kv0 + 32 + lq) * Dn + kk * 16 + hi * 8);
    }
  }

  for (int i = 0; i < cnt; ++i) {
    const int kv0 = (tbase + i) * 64;

    // S^T = K Q^T (uses kf loaded last iter / prologue)
    f32x16 s0 = {}, s1 = {};
    __builtin_amdgcn_s_setprio(1);
#pragma unroll
    for (int kk = 0; kk < 4; ++kk) {
      s0 = mfma_bf16_32x32x16(kf0[kk], qf[kk], s0);
      s1 = mfma_bf16_32x32x16(kf1[kk], qf[kk], s1);
    }
    __builtin_amdgcn_s_setprio(0);

    // issue V(i) gathers (consumed by PV below; softmax covers the latency)
    bf16x8 vf0[4], vf1[4];
#pragma unroll
    for (int kk = 0; kk < 4; ++kk) {
      vf0[kk] = *reinterpret_cast<const bf16x8*>(vb + (size_t)lq * Sn + kv0 + kk * 16 + hi * 8);
      vf1[kk] = *reinterpret_cast<const bf16x8*>(vb + (size_t)(32 + lq) * Sn + kv0 + kk * 16 + hi * 8);
    }
    // issue K(i+1) gathers (consumed at next iter's QK)
    if (i + 1 < cnt) {
      const size_t kvn = (size_t)(tbase + i + 1) * 64;
#pragma unroll
      for (int kk = 0; kk < 4; ++kk) {
        kf0[kk] = *reinterpret_cast<const bf16x8*>(kb + (kvn + lq) * Dn + kk * 16 + hi * 8);
        kf1[kk] = *reinterpret_cast<const bf16x8*>(kb + (kvn + 32 + lq) * Dn + kk * 16 + hi * 8);
      }
    }

    // causal mask (diagonal-crossing tiles only)
    if (kv0 + 63 > qrow0) {
      const int qg = qrow0 + lq;
#pragma unroll
      for (int r = 0; r < 16; ++r) {
        const int kvl = (r & 3) + 8 * (r >> 2) + 4 * hi;
        if (kv0 + kvl > qg)      s0[r] = -1e30f;
        if (kv0 + 32 + kvl > qg) s1[r] = -1e30f;
      }
    }

    // in-register online softmax (per-lane row q = lq), defer-max (T13)
    float mx[8];
#pragma unroll
    for (int i2 = 0; i2 < 8; ++i2)
      mx[i2] = fmaxf(fmaxf(s0[i2], s0[i2 + 8]), fmaxf(s1[i2], s1[i2 + 8]));
#pragma unroll
    for (int i2 = 0; i2 < 4; ++i2) mx[i2] = fmaxf(mx[i2], mx[i2 + 4]);
    const float tmax_own = fmaxf(fmaxf(mx[0], mx[1]), fmaxf(mx[2], mx[3]));
    const float tmax = cross_half_max(tmax_own);

    float alpha = 1.0f;
    if (!__all(tmax <= mrow + 8.0f)) {
      const float mn = fmaxf(mrow, tmax);
      alpha = fast_exp2(mrow - mn);
      mrow = mn;
#pragma unroll
      for (int r = 0; r < 16; ++r) { oacc0[r] *= alpha; oacc1[r] *= alpha; }
    }
#pragma unroll
    for (int r = 0; r < 16; ++r) {
      s0[r] = fast_exp2(s0[r] - mrow);
      s1[r] = fast_exp2(s1[r] - mrow);
    }
    float sm[8];
#pragma unroll
    for (int i2 = 0; i2 < 8; ++i2)
      sm[i2] = (s0[i2] + s0[i2 + 8]) + (s1[i2] + s1[i2 + 8]);
#pragma unroll
    for (int i2 = 0; i2 < 4; ++i2) sm[i2] += sm[i2 + 4];
    float rsum = (sm[0] + sm[1]) + (sm[2] + sm[3]);
    rsum = cross_half_add(rsum);
    lsum = lsum * alpha + rsum;

    // P -> bf16 B-fragments; cross-half exchange (2 shfl per c2)
    u32x4 pw[4];
#pragma unroll
    for (int c2 = 0; c2 < 4; ++c2) {
      const f32x16& S = (c2 < 2) ? s0 : s1;
      const int base = (c2 & 1) * 8;
      const unsigned u0 = cvt_pk_bf16(S[base + 0], S[base + 1]);
      const unsigned u1 = cvt_pk_bf16(S[base + 2], S[base + 3]);
      const unsigned u2 = cvt_pk_bf16(S[base + 4], S[base + 5]);
      const unsigned u3 = cvt_pk_bf16(S[base + 6], S[base + 7]);
      const unsigned r1 = shfl32u(hi ? u0 : u2);
      const unsigned r2 = shfl32u(hi ? u1 : u3);
      pw[c2][0] = hi ? r1 : u0;
      pw[c2][1] = hi ? r2 : u1;
      pw[c2][2] = hi ? u2 : r1;
      pw[c2][3] = hi ? u3 : r2;
    }

    // O^T += V^T P
    __builtin_amdgcn_s_setprio(1);
#pragma unroll
    for (int kk = 0; kk < 4; ++kk) {
      const bf16x8 pf = __builtin_bit_cast(bf16x8, pw[kk]);
      oacc0 = mfma_bf16_32x32x16(vf0[kk], pf, oacc0);
      oacc1 = mfma_bf16_32x32x16(vf1[kk], pf, oacc1);
    }
    __builtin_amdgcn_s_setprio(0);
  }

  // ---- merge: wave1 publishes (m, l, O) via LDS; wave0 combines and stores ----
  if (w == 1) {
#pragma unroll
    for (int r = 0; r < 16; ++r) {
      const int d = (r & 3) + 8 * (r >> 2) + 4 * hi;
      OpL[lq * 65 + d]      = oacc0[r];
      OpL[lq * 65 + 32 + d] = oacc1[r];
    }
    if (hi == 0) { MlL[lq] = mrow; MlL[32 + lq] = lsum; }
  }
  __syncthreads();

  if (w == 0) {
    const float m1 = MlL[lq], l1 = MlL[32 + lq];
    const float mm = fmaxf(mrow, m1);
    const float a0 = fast_exp2(mrow - mm);
    const float a1 = fast_exp2(m1 - mm);
    const float inv = 1.0f / (lsum * a0 + l1 * a1);

    bf16* crow = ctx + ((size_t)b * Sn + qrow0 + lq) * Dn + h * HDn;
#pragma unroll
    for (int dt = 0; dt < 2; ++dt) {
      const f32x16& O = dt ? oacc1 : oacc0;
#pragma unroll
      for (int g2 = 0; g2 < 4; ++g2) {
        bf16x4 o4;
#pragma unroll
        for (int jj = 0; jj < 4; ++jj) {
          const int d = dt * 32 + 8 * g2 + 4 * hi + jj;
          o4[jj] = (bf16)((O[g2 * 4 + jj] * a0 + OpL[lq * 65 + d] * a1) * inv);
        }
        *reinterpret_cast<bf16x4*>(crow + dt * 32 + g2 * 8 + hi * 4) = o4;
      }
    }
  }
}

// ---------------- launch ----------------
extern "C" void kernel_launch(void* const* d_in, const int* in_sizes, int n_in,
                              void* d_out, int out_size, void* d_ws, size_t ws_size,
                              hipStream_t stream) {
  const float* q  = (const float*)d_in[0];
  const float* k  = (const float*)d_in[1];
  const float* v  = (const float*)d_in[2];
  // d_in[3] = causal mask (structure known; unused)
  const float* Wq = (const float*)d_in[4];
  const float* Wk = (const float*)d_in[5];
  const float* Wv = (const float*)d_in[6];
  const float* Wo = (const float*)d_in[7];

  constexpr size_t BSD = (size_t)Bn * Sn * Dn;
  constexpr size_t DD  = (size_t)Dn * Dn;

  char* p = (char*)d_ws;
  bf16* qbf = (bf16*)p; p += BSD * 2;  // reused as ctx after gemm_qkv
  bf16* kbf = (bf16*)p; p += BSD * 2;  // reused as vt  after gemm_qkv
  bf16* vbf = (bf16*)p; p += BSD * 2;
  bf16* qpb = (bf16*)p; p += BSD * 2;
  bf16* kpb = (bf16*)p; p += BSD * 2;
  bf16* vpb = (bf16*)p; p += BSD * 2;
  bf16* wqb = (bf16*)p; p += DD * 2;
  bf16* wkb = (bf16*)p; p += DD * 2;
  bf16* wvb = (bf16*)p; p += DD * 2;
  bf16* wob = (bf16*)p; p += DD * 2;
  bf16* vtb  = kbf;   // kbf dead after gemm_qkv
  bf16* ctxb = qbf;   // qbf dead after gemm_qkv

  // fold softmax scale (1/sqrt(64)=1/8) and log2(e) into Wq for exp2-domain softmax
  const float wq_scale = 0.125f * 1.4426950408889634f;

  cvt_qkv<<<dim3(1024, 1, 3), 256, 0, stream>>>(q, k, v, qbf, kbf, vbf, (int)(BSD / 4));
  cvt_w<<<dim3(256, 1, 4), 256, 0, stream>>>(Wq, Wk, Wv, Wo, wqb, wkb, wvb, wob,
                                             (int)(DD / 4), wq_scale);

  gemm_qkv<<<dim3(Dn / 128, (Bn * Sn) / 128, 3), 256, 0, stream>>>(
      qbf, wqb, qpb, kbf, wkb, kpb, vbf, wvb, vpb);

  transpose_bsd<<<dim3(Sn / 64, Dn / 64, Bn), 256, 0, stream>>>(vpb, vtb);

  flash_attn<<<dim3(2048), 128, 0, stream>>>(qpb, kpb, vtb, ctxb);

  gemm_out_f32<<<dim3(Dn / 128, (Bn * Sn) / 128), 256, 0, stream>>>(ctxb, wob, (float*)d_out);

  (void)in_sizes; (void)n_in; (void)out_size; (void)ws_size;
}

// Round 13
// 126.804 us; speedup vs baseline: 1.3242x; 1.3242x over previous
//
#include <hip/hip_runtime.h>

typedef __bf16 bf16;
typedef __bf16 bf16x4 __attribute__((ext_vector_type(4)));
typedef __bf16 bf16x8 __attribute__((ext_vector_type(8)));
typedef float f32x4 __attribute__((ext_vector_type(4)));
typedef float f32x16 __attribute__((ext_vector_type(16)));
typedef unsigned u32x4 __attribute__((ext_vector_type(4)));

static constexpr int Bn = 2, Sn = 2048, Dn = 1024, Hn = 16, HDn = 64;

__device__ __forceinline__ void gload_lds16(const void* g, void* l) {
  __builtin_amdgcn_global_load_lds((__attribute__((address_space(1))) void*)g,
                                   (__attribute__((address_space(3))) void*)l, 16, 0, 0);
}

__device__ __forceinline__ f32x4 mfma_bf16_16x16x32(bf16x8 a, bf16x8 b, f32x4 c) {
  return __builtin_amdgcn_mfma_f32_16x16x32_bf16(a, b, c, 0, 0, 0);
}

__device__ __forceinline__ f32x16 mfma_bf16_32x32x16(bf16x8 a, bf16x8 b, f32x16 c) {
  return __builtin_amdgcn_mfma_f32_32x32x16_bf16(a, b, c, 0, 0, 0);
}

__device__ __forceinline__ float fast_exp2(float x) {
  float r;
  asm("v_exp_f32 %0, %1" : "=v"(r) : "v"(x));
  return r;
}

__device__ __forceinline__ unsigned cvt_pk_bf16(float lo, float hi) {
  unsigned r;
  asm("v_cvt_pk_bf16_f32 %0, %1, %2" : "=v"(r) : "v"(lo), "v"(hi));
  return r;
}

// Cross-half (lane ^ 32) combine via known-good shfl_xor (ds_bpermute path).
__device__ __forceinline__ float cross_half_max(float v) {
  return fmaxf(v, __shfl_xor(v, 32, 64));
}
__device__ __forceinline__ float cross_half_add(float v) {
  return v + __shfl_xor(v, 32, 64);
}
__device__ __forceinline__ unsigned shfl32u(unsigned u) {
  return (unsigned)__shfl_xor((int)u, 32, 64);
}

#define WAITCNT_VM(N) asm volatile("s_waitcnt vmcnt(" #N ")" ::: "memory")
#define WAITCNT_LGKM0 asm volatile("s_waitcnt lgkmcnt(0)" ::: "memory")

// ---------------- fp32 -> bf16 converts (fused launches) ----------------
__global__ __launch_bounds__(256) void cvt_qkv(const float* __restrict__ a0,
                                               const float* __restrict__ a1,
                                               const float* __restrict__ a2,
                                               bf16* __restrict__ o0,
                                               bf16* __restrict__ o1,
                                               bf16* __restrict__ o2, int n4) {
  const float* in = blockIdx.z == 0 ? a0 : (blockIdx.z == 1 ? a1 : a2);
  bf16* out = blockIdx.z == 0 ? o0 : (blockIdx.z == 1 ? o1 : o2);
  int i = blockIdx.x * 256 + threadIdx.x;
  const int stride = gridDim.x * 256;
  for (; i < n4; i += stride) {
    float4 v = reinterpret_cast<const float4*>(in)[i];
    bf16x4 o;
    o[0] = (bf16)v.x; o[1] = (bf16)v.y; o[2] = (bf16)v.z; o[3] = (bf16)v.w;
    reinterpret_cast<bf16x4*>(out)[i] = o;
  }
}

__global__ __launch_bounds__(256) void cvt_w(const float* __restrict__ a0,
                                             const float* __restrict__ a1,
                                             const float* __restrict__ a2,
                                             const float* __restrict__ a3,
                                             bf16* __restrict__ o0,
                                             bf16* __restrict__ o1,
                                             bf16* __restrict__ o2,
                                             bf16* __restrict__ o3,
                                             int n4, float s0) {
  const float* in; bf16* out; float s = 1.0f;
  switch (blockIdx.z) {
    case 0: in = a0; out = o0; s = s0; break;  // Wq gets softmax scale * log2(e)
    case 1: in = a1; out = o1; break;
    case 2: in = a2; out = o2; break;
    default: in = a3; out = o3; break;
  }
  int i = blockIdx.x * 256 + threadIdx.x;
  const int stride = gridDim.x * 256;
  for (; i < n4; i += stride) {
    float4 v = reinterpret_cast<const float4*>(in)[i];
    bf16x4 o;
    o[0] = (bf16)(v.x * s); o[1] = (bf16)(v.y * s);
    o[2] = (bf16)(v.z * s); o[3] = (bf16)(v.w * s);
    reinterpret_cast<bf16x4*>(out)[i] = o;
  }
}

// ---------------- GEMM: C[M,N] = A[M,K] * B[N,K]^T  (m97 structure, bf16 A) -------------
__device__ __forceinline__ void store_out(float* C, size_t i, float v) { C[i] = v; }
__device__ __forceinline__ void store_out(bf16* C, size_t i, float v) { C[i] = (bf16)v; }

template <typename OutT>
__device__ __forceinline__ void gemm_bt_dev(const bf16* __restrict__ A,
                                            const bf16* __restrict__ Bw,
                                            OutT* __restrict__ C,
                                            int K, int N) {
  const int t = threadIdx.x;
  const int l = t & 63, w = t >> 6;
  const int wr = w >> 1, wc = w & 1;
  const int lc = l & 15, lg = l >> 4;
  const int row0 = blockIdx.y * 128;
  const int col0 = blockIdx.x * 128;

  __shared__ bf16 As[128 * 32];
  __shared__ bf16 Bs[128 * 32];

  f32x4 acc[4][4] = {};

  for (int k0 = 0; k0 < K; k0 += 32) {
#pragma unroll
    for (int i = 0; i < 2; ++i) {
      const int c = i * 256 + t;
      const int r = c >> 2;
      const int scc = (c & 3) ^ (r & 3);
      gload_lds16(A + (size_t)(row0 + r) * K + k0 + scc * 8, As + c * 8);
      gload_lds16(Bw + (size_t)(col0 + r) * K + k0 + scc * 8, Bs + c * 8);
    }
    __syncthreads();

    bf16x8 af[4], bfr[4];
#pragma unroll
    for (int m = 0; m < 4; ++m) {
      const int r = wr * 64 + m * 16 + lc;
      af[m] = *reinterpret_cast<const bf16x8*>(As + r * 32 + ((lg ^ (r & 3)) * 8));
    }
#pragma unroll
    for (int n = 0; n < 4; ++n) {
      const int r = wc * 64 + n * 16 + lc;
      bfr[n] = *reinterpret_cast<const bf16x8*>(Bs + r * 32 + ((lg ^ (r & 3)) * 8));
    }
#pragma unroll
    for (int m = 0; m < 4; ++m)
#pragma unroll
      for (int n = 0; n < 4; ++n)
        acc[m][n] = mfma_bf16_16x16x32(af[m], bfr[n], acc[m][n]);
    __syncthreads();
  }

#pragma unroll
  for (int m = 0; m < 4; ++m) {
    const int rbase = row0 + wr * 64 + m * 16 + lg * 4;
#pragma unroll
    for (int n = 0; n < 4; ++n) {
      const int col = col0 + wc * 64 + n * 16 + lc;
#pragma unroll
      for (int j = 0; j < 4; ++j)
        store_out(C, (size_t)(rbase + j) * N + col, acc[m][n][j]);
    }
  }
}

__global__ __launch_bounds__(256) void gemm_qkv(
    const bf16* __restrict__ qa, const bf16* __restrict__ wq, bf16* __restrict__ qo,
    const bf16* __restrict__ ka, const bf16* __restrict__ wk, bf16* __restrict__ ko,
    const bf16* __restrict__ va, const bf16* __restrict__ wv, bf16* __restrict__ vo) {
  const bf16 *A, *Bw;
  bf16* C;
  if (blockIdx.z == 0)      { A = qa; Bw = wq; C = qo; }
  else if (blockIdx.z == 1) { A = ka; Bw = wk; C = ko; }
  else                      { A = va; Bw = wv; C = vo; }
  gemm_bt_dev<bf16>(A, Bw, C, Dn, Dn);
}

__global__ __launch_bounds__(256) void gemm_out_f32(const bf16* __restrict__ A,
                                                    const bf16* __restrict__ Bw,
                                                    float* __restrict__ C) {
  gemm_bt_dev<float>(A, Bw, C, Dn, Dn);
}

// ---------------- per-batch transpose (S x D) -> (D x S) for V ----------------
__global__ __launch_bounds__(256) void transpose_bsd(const bf16* __restrict__ in,
                                                     bf16* __restrict__ out) {
  __shared__ bf16 tile[64][66];
  const int s0 = blockIdx.x * 64, d0 = blockIdx.y * 64, b = blockIdx.z;
  const int t = threadIdx.x;
#pragma unroll
  for (int i = 0; i < 2; ++i) {
    const int c = i * 256 + t;
    const int r = c >> 3, cc = (c & 7) * 8;
    const bf16x8 v = *reinterpret_cast<const bf16x8*>(
        in + ((size_t)b * Sn + s0 + r) * Dn + d0 + cc);
#pragma unroll
    for (int j = 0; j < 8; ++j) tile[r][cc + j] = v[j];
  }
  __syncthreads();
#pragma unroll
  for (int i = 0; i < 2; ++i) {
    const int c = i * 256 + t;
    const int r = c >> 3, cc = (c & 7) * 8;
    bf16x8 v;
#pragma unroll
    for (int j = 0; j < 8; ++j) v[j] = tile[cc + j][r];
    *reinterpret_cast<bf16x8*>(out + ((size_t)b * Dn + d0 + r) * Sn + s0 + cc) = v;
  }
}

// ---------------- causal flash attention (v11: KV-split + paired qt, uniform) ------------
// R11 (in-block KV-split) + R8 (complementary-qt pairing): each 8-wave block runs two
// phases, qtA=15-pid then qtB=pid; each phase splits its 2qt+2 KV tiles across wave
// halves (chunks of cnt=qt+1). Per-wave work = 17 tiles for EVERY block -> 256 blocks,
// 1/CU resident start-to-finish, 8 waves/CU = 2/SIMD sustained, zero tail (R11's
// grid==capacity meant no refill and cnt in [1,16] decayed occupancy to ~1.1/SIMD).
// Loop body / merge identical to R11 (race-fix barrier included). Phase-top barrier
// protects epilogue-slab reads from next phase's STAGE writes (R8-proven); both halves
// have equal cnt per phase so barrier counts match.
// XCD pinning: XCD = n%8; g=(n&7)+8*(n>>6) in [0,32): 4 (h,b) groups per XCD (2MB L2).
__global__ __launch_bounds__(512) void flash_attn(const bf16* __restrict__ qp,
                                                  const bf16* __restrict__ kp,
                                                  const bf16* __restrict__ vt,
                                                  bf16* __restrict__ ctx) {
  const int n = blockIdx.x;
  const int g = (n & 7) + 8 * (n >> 6);
  const int pid = (n >> 3) & 7;
  const int h = g & 15;
  const int b = g >> 4;
  const int t = threadIdx.x, w = t >> 6, l = t & 63;
  const int lq = l & 31, hi = l >> 5;
  const int half = w >> 2;             // 0: chunk0 waves, 1: chunk1 waves

  __shared__ char smem[81920];
  char* my = smem + half * 40960;      // my half's staging region

  // staging: 256 threads per half; 2 K-chunks + 2 V-chunks per thread per tile
  const int tl = t & 255;
  const int rl = tl >> 3;
  const int scc = (tl & 7) ^ (rl & 7);
  const bf16* kbase = kp + ((size_t)b * Sn + rl) * Dn + h * HDn + scc * 8;
  const bf16* vbase = vt + ((size_t)b * Dn + h * HDn + rl) * Sn + scc * 8;

  for (int ph = 0; ph < 2; ++ph) {
    const int qt = ph ? pid : 15 - pid;
    const int qrow0 = qt * 128 + (w & 3) * 32;
    const int cnt = qt + 1;            // tiles per chunk (same for both halves)
    const int tbase = half * cnt;      // first (global) tile index of my chunk

    auto STAGE = [&](int i) {  // local tile i of my chunk (4 gload_lds / thread)
      const int kv0 = (tbase + i) * 64;
      char* Kd = my + (i & 1) * 8192 + tl * 16;
      char* Vd = my + 16384 + (i % 3) * 8192 + tl * 16;
      const bf16* ks = kbase + (size_t)kv0 * Dn;
      const bf16* vs = vbase + kv0;
#pragma unroll
      for (int ii = 0; ii < 2; ++ii) {
        gload_lds16(ks + (size_t)ii * 32 * Dn, Kd + ii * 4096);
        gload_lds16(vs + (size_t)ii * 32 * Sn, Vd + ii * 4096);
      }
    };

    // Q fragments: lane holds q=lq, k = kk*16 + hi*8 + e
    bf16x8 qf[4];
#pragma unroll
    for (int kk = 0; kk < 4; ++kk)
      qf[kk] = *reinterpret_cast<const bf16x8*>(
          qp + ((size_t)b * Sn + qrow0 + lq) * Dn + h * HDn + kk * 16 + hi * 8);

    f32x16 oacc0 = {}, oacc1 = {};  // O^T partial: d 0..31 / 32..63, q = lq
    float mrow = -1e30f, lsum = 0.0f;

    auto QK = [&](int i, f32x16& s0_, f32x16& s1_) {
      const char* Kc = my + (i & 1) * 8192;
      __builtin_amdgcn_s_setprio(1);
#pragma unroll
      for (int kk = 0; kk < 4; ++kk) {
        const int ch = kk * 2 + hi;
        const int r0 = lq, r1 = 32 + lq;
        const bf16x8 k0 = *reinterpret_cast<const bf16x8*>(Kc + r0 * 128 + ((ch ^ (r0 & 7)) << 4));
        const bf16x8 k1 = *reinterpret_cast<const bf16x8*>(Kc + r1 * 128 + ((ch ^ (r1 & 7)) << 4));
        s0_ = mfma_bf16_32x32x16(k0, qf[kk], s0_);
        s1_ = mfma_bf16_32x32x16(k1, qf[kk], s1_);
      }
      __builtin_amdgcn_s_setprio(0);
    };

    auto SMPV = [&](int i, f32x16& s0, f32x16& s1) {
      const int kv0 = (tbase + i) * 64;
      const char* Vc = my + 16384 + (i % 3) * 8192;

      if (kv0 + 63 > qrow0) {  // causal mask (diagonal-crossing tiles only)
        const int qg = qrow0 + lq;
#pragma unroll
        for (int r = 0; r < 16; ++r) {
          const int kvl = (r & 3) + 8 * (r >> 2) + 4 * hi;
          if (kv0 + kvl > qg)      s0[r] = -1e30f;
          if (kv0 + 32 + kvl > qg) s1[r] = -1e30f;
        }
      }

      float mx[8];
#pragma unroll
      for (int i2 = 0; i2 < 8; ++i2)
        mx[i2] = fmaxf(fmaxf(s0[i2], s0[i2 + 8]), fmaxf(s1[i2], s1[i2 + 8]));
#pragma unroll
      for (int i2 = 0; i2 < 4; ++i2) mx[i2] = fmaxf(mx[i2], mx[i2 + 4]);
      const float tmax_own = fmaxf(fmaxf(mx[0], mx[1]), fmaxf(mx[2], mx[3]));
      const float tmax = cross_half_max(tmax_own);

      float alpha = 1.0f;
      if (!__all(tmax <= mrow + 8.0f)) {  // defer-max (T13)
        const float mn = fmaxf(mrow, tmax);
        alpha = fast_exp2(mrow - mn);
        mrow = mn;
#pragma unroll
        for (int r = 0; r < 16; ++r) { oacc0[r] *= alpha; oacc1[r] *= alpha; }
      }
#pragma unroll
      for (int r = 0; r < 16; ++r) {
        s0[r] = fast_exp2(s0[r] - mrow);
        s1[r] = fast_exp2(s1[r] - mrow);
      }
      float sm[8];
#pragma unroll
      for (int i2 = 0; i2 < 8; ++i2)
        sm[i2] = (s0[i2] + s0[i2 + 8]) + (s1[i2] + s1[i2 + 8]);
#pragma unroll
      for (int i2 = 0; i2 < 4; ++i2) sm[i2] += sm[i2 + 4];
      float rsum = (sm[0] + sm[1]) + (sm[2] + sm[3]);
      rsum = cross_half_add(rsum);
      lsum = lsum * alpha + rsum;

      u32x4 pw[4];
#pragma unroll
      for (int c2 = 0; c2 < 4; ++c2) {
        const f32x16& S = (c2 < 2) ? s0 : s1;
        const int base = (c2 & 1) * 8;
        const unsigned u0 = cvt_pk_bf16(S[base + 0], S[base + 1]);
        const unsigned u1 = cvt_pk_bf16(S[base + 2], S[base + 3]);
        const unsigned u2 = cvt_pk_bf16(S[base + 4], S[base + 5]);
        const unsigned u3 = cvt_pk_bf16(S[base + 6], S[base + 7]);
        const unsigned r1 = shfl32u(hi ? u0 : u2);
        const unsigned r2 = shfl32u(hi ? u1 : u3);
        pw[c2][0] = hi ? r1 : u0;
        pw[c2][1] = hi ? r2 : u1;
        pw[c2][2] = hi ? u2 : r1;
        pw[c2][3] = hi ? u3 : r2;
      }

      __builtin_amdgcn_s_setprio(1);
#pragma unroll
      for (int kk = 0; kk < 4; ++kk) {
        const bf16x8 pf = __builtin_bit_cast(bf16x8, pw[kk]);
        const int ch = kk * 2 + hi;
        const int r0 = lq, r1 = 32 + lq;
        const bf16x8 v0 = *reinterpret_cast<const bf16x8*>(Vc + r0 * 128 + ((ch ^ (r0 & 7)) << 4));
        const bf16x8 v1 = *reinterpret_cast<const bf16x8*>(Vc + r1 * 128 + ((ch ^ (r1 & 7)) << 4));
        oacc0 = mfma_bf16_32x32x16(v0, pf, oacc0);
        oacc1 = mfma_bf16_32x32x16(v1, pf, oacc1);
      }
      __builtin_amdgcn_s_setprio(0);
    };

    // phase-top barrier: prior-phase epilogue LDS reads retired before STAGE writes
    __builtin_amdgcn_s_barrier();
    __builtin_amdgcn_sched_barrier(0);

    // ---- pipelined chunk loop (cnt tiles) ----
    STAGE(0);
    if (cnt > 1) { STAGE(1); WAITCNT_VM(4); } else { WAITCNT_VM(0); }
    __builtin_amdgcn_sched_barrier(0);
    __builtin_amdgcn_s_barrier();
    __builtin_amdgcn_sched_barrier(0);

    f32x16 sp0 = {}, sp1 = {};
    if (tbase * 64 <= qrow0 + 31) QK(0, sp0, sp1);

    for (int i = 0; i < cnt; ++i) {
      WAITCNT_VM(0);
      __builtin_amdgcn_sched_barrier(0);
      __builtin_amdgcn_s_barrier();
      __builtin_amdgcn_sched_barrier(0);

      if (i + 2 < cnt) STAGE(i + 2);
      f32x16 sn0 = {}, sn1 = {};
      if (i + 1 < cnt && (tbase + i + 1) * 64 <= qrow0 + 31) QK(i + 1, sn0, sn1);
      if ((tbase + i) * 64 <= qrow0 + 31) SMPV(i, sp0, sp1);
      sp0 = sn0; sp1 = sn1;
      WAITCNT_LGKM0;
    }

    // race-fix barrier (R10 lesson): quiesce all staging-region reads before the
    // publish overwrites chunk0's K/V bytes with f32 partials.
    __builtin_amdgcn_s_barrier();
    __builtin_amdgcn_sched_barrier(0);

    // ---- merge: chunk1 publishes partials via LDS (staging regions now dead) ----
    float* Op = (float*)smem;
    float* Ml = (float*)(smem + 33280);
    const int lrow = (w & 3) * 32 + lq;

    if (half == 1) {
#pragma unroll
      for (int r = 0; r < 16; ++r) {
        const int d = (r & 3) + 8 * (r >> 2) + 4 * hi;
        Op[lrow * 65 + d]      = oacc0[r];
        Op[lrow * 65 + 32 + d] = oacc1[r];
      }
      if (hi == 0) { Ml[lrow] = mrow; Ml[128 + lrow] = lsum; }
    }
    WAITCNT_LGKM0;
    __builtin_amdgcn_s_barrier();
    __builtin_amdgcn_sched_barrier(0);

    if (half == 0) {
      const float m1 = Ml[lrow], l1 = Ml[128 + lrow];
      const float mm = fmaxf(mrow, m1);
      const float a0 = fast_exp2(mrow - mm);
      const float a1 = fast_exp2(m1 - mm);
      const float inv = 1.0f / (lsum * a0 + l1 * a1);

      bf16* ep = (bf16*)(smem + 40960 + w * 4608);  // [32 q][72 d] bf16 (half1 region)
#pragma unroll
      for (int dt = 0; dt < 2; ++dt) {
        const f32x16& O = dt ? oacc1 : oacc0;
#pragma unroll
        for (int g2 = 0; g2 < 4; ++g2) {
          bf16x4 o4;
#pragma unroll
          for (int jj = 0; jj < 4; ++jj) {
            const int d = dt * 32 + 8 * g2 + 4 * hi + jj;
            const float o1 = Op[lrow * 65 + d];
            o4[jj] = (bf16)((O[g2 * 4 + jj] * a0 + o1 * a1) * inv);
          }
          const int d0 = dt * 32 + g2 * 8 + hi * 4;
          *reinterpret_cast<bf16x4*>(&ep[lq * 72 + d0]) = o4;
        }
      }
      WAITCNT_LGKM0;
      __builtin_amdgcn_sched_barrier(0);
#pragma unroll
      for (int i = 0; i < 4; ++i) {
        const int q = i * 8 + (l >> 3);
        const int d0 = (l & 7) * 8;
        const bf16x8 vv = *reinterpret_cast<const bf16x8*>(&ep[q * 72 + d0]);
        *reinterpret_cast<bf16x8*>(
            &ctx[((size_t)b * Sn + qrow0 - (w & 3) * 32 + (w & 3) * 32 + q) * Dn + h * HDn + d0]) = vv;
      }
    }
  }
}

// ---------------- launch ----------------
extern "C" void kernel_launch(void* const* d_in, const int* in_sizes, int n_in,
                              void* d_out, int out_size, void* d_ws, size_t ws_size,
                              hipStream_t stream) {
  const float* q  = (const float*)d_in[0];
  const float* k  = (const float*)d_in[1];
  const float* v  = (const float*)d_in[2];
  // d_in[3] = causal mask (structure known; unused)
  const float* Wq = (const float*)d_in[4];
  const float* Wk = (const float*)d_in[5];
  const float* Wv = (const float*)d_in[6];
  const float* Wo = (const float*)d_in[7];

  constexpr size_t BSD = (size_t)Bn * Sn * Dn;
  constexpr size_t DD  = (size_t)Dn * Dn;

  char* p = (char*)d_ws;
  bf16* qbf = (bf16*)p; p += BSD * 2;  // reused as ctx after gemm_qkv
  bf16* kbf = (bf16*)p; p += BSD * 2;  // reused as vt  after gemm_qkv
  bf16* vbf = (bf16*)p; p += BSD * 2;
  bf16* qpb = (bf16*)p; p += BSD * 2;
  bf16* kpb = (bf16*)p; p += BSD * 2;
  bf16* vpb = (bf16*)p; p += BSD * 2;
  bf16* wqb = (bf16*)p; p += DD * 2;
  bf16* wkb = (bf16*)p; p += DD * 2;
  bf16* wvb = (bf16*)p; p += DD * 2;
  bf16* wob = (bf16*)p; p += DD * 2;
  bf16* vtb  = kbf;   // kbf dead after gemm_qkv
  bf16* ctxb = qbf;   // qbf dead after gemm_qkv

  // fold softmax scale (1/sqrt(64)=1/8) and log2(e) into Wq for exp2-domain softmax
  const float wq_scale = 0.125f * 1.4426950408889634f;

  cvt_qkv<<<dim3(1024, 1, 3), 256, 0, stream>>>(q, k, v, qbf, kbf, vbf, (int)(BSD / 4));
  cvt_w<<<dim3(256, 1, 4), 256, 0, stream>>>(Wq, Wk, Wv, Wo, wqb, wkb, wvb, wob,
                                             (int)(DD / 4), wq_scale);

  gemm_qkv<<<dim3(Dn / 128, (Bn * Sn) / 128, 3), 256, 0, stream>>>(
      qbf, wqb, qpb, kbf, wkb, kpb, vbf, wvb, vpb);

  transpose_bsd<<<dim3(Sn / 64, Dn / 64, Bn), 256, 0, stream>>>(vpb, vtb);

  flash_attn<<<dim3(256), 512, 0, stream>>>(qpb, kpb, vtb, ctxb);

  gemm_out_f32<<<dim3(Dn / 128, (Bn * Sn) / 128), 256, 0, stream>>>(ctxb, wob, (float*)d_out);

  (void)in_sizes; (void)n_in; (void)out_size; (void)ws_size;
}